// Round 1
// baseline (170.039 us; speedup 1.0000x reference)
//
#include <hip/hip_runtime.h>

#define BATCH 128
#define SENS 128
#define UNITS 512
#define MOTOR 64
#define UNFOLDS 6
#define L2E 1.442695040888963f
#define EPS 1e-8f

// ---------------------------------------------------------------------------
// Fold recurrent weights: sgl = sigma*log2e, msl = mu*sigma*log2e,
// wm = w*mask, we = w*mask*erev.  One-shot elementwise over U*U.
// ---------------------------------------------------------------------------
__global__ __launch_bounds__(256) void fold_kernel(
    const float* __restrict__ sigma, const float* __restrict__ mu,
    const float* __restrict__ w, const float* __restrict__ erev,
    const float* __restrict__ mask,
    float* __restrict__ sgl, float* __restrict__ msl,
    float* __restrict__ wm, float* __restrict__ we)
{
    int i = blockIdx.x * 256 + threadIdx.x;
    if (i < UNITS * UNITS) {
        float sg = sigma[i] * L2E;
        sgl[i] = sg;
        msl[i] = mu[i] * sg;
        float wmv = w[i] * mask[i];
        wm[i] = wmv;
        we[i] = wmv * erev[i];
    }
}

// ---------------------------------------------------------------------------
// Sensory accumulators: wns[b,u] = sum_s act*erev, wds[b,u] = sum_s act
// act = sw * sigmoid((x - smu)*ssig) * smask,  x = inputs*input_w + input_b
// One thread per (b,u); u fastest -> coalesced weight reads; b uniform/block.
// ---------------------------------------------------------------------------
__global__ __launch_bounds__(256) void sensory_kernel(
    const float* __restrict__ inputs, const float* __restrict__ input_w,
    const float* __restrict__ input_b,
    const float* __restrict__ ssig, const float* __restrict__ smu,
    const float* __restrict__ sw, const float* __restrict__ serev,
    const float* __restrict__ smask,
    float* __restrict__ wns, float* __restrict__ wds)
{
    int idx = blockIdx.x * 256 + threadIdx.x;   // b*512 + u
    int b = idx >> 9;
    int u = idx & (UNITS - 1);
    float num = 0.f, den = 0.f;
    #pragma unroll 4
    for (int s = 0; s < SENS; ++s) {
        float x = __builtin_fmaf(inputs[b * SENS + s], input_w[s], input_b[s]);
        int k = s * UNITS + u;
        float t = (smu[k] - x) * ssig[k] * L2E;      // -(x-mu)*sig*log2e
        float e = __builtin_amdgcn_exp2f(t);
        float sg = __builtin_amdgcn_rcpf(1.0f + e);  // sigmoid
        float a = sw[k] * sg * smask[k];
        num = __builtin_fmaf(a, serev[k], num);
        den += a;
    }
    wns[idx] = num;
    wds[idx] = den;
}

// ---------------------------------------------------------------------------
// One ODE unfold.  Block tile: 16 batches x 16 units, v split in 2 halves
// (512 threads).  Source state staged in LDS (padded rows).  Weights read
// from L2 (coalesced, reused 16x across batches per fetch).
// ---------------------------------------------------------------------------
#define BT 16
#define UT 16

__global__ __launch_bounds__(512) void unfold_kernel(
    const float* __restrict__ src,     // [B,U] current state
    float* __restrict__ dst,           // [B,U] next state
    const float* __restrict__ sgl, const float* __restrict__ msl,
    const float* __restrict__ wm, const float* __restrict__ we,
    const float* __restrict__ wns, const float* __restrict__ wds,
    const float* __restrict__ gleak, const float* __restrict__ vleak,
    const float* __restrict__ cm,
    const float* __restrict__ output_w, const float* __restrict__ output_b,
    float* __restrict__ out_motor,     // [B,MOTOR]
    int last)
{
    __shared__ float st[BT][UNITS + 4];        // +4 pad -> conflict-free
    __shared__ float cnum[BT * UT];
    __shared__ float cden[BT * UT];

    int bt = blockIdx.x >> 5;                  // 8 batch tiles
    int ut = blockIdx.x & 31;                  // 32 unit tiles
    int b0 = bt * BT;
    int u0 = ut * UT;

    // stage state tile [16][512] into LDS, coalesced
    for (int i = threadIdx.x; i < BT * UNITS; i += 512) {
        int bl = i >> 9;
        int col = i & (UNITS - 1);
        st[bl][col] = src[(b0 + bl) * UNITS + col];
    }
    __syncthreads();

    int vh   = threadIdx.x >> 8;               // 0/1: v half
    int rest = threadIdx.x & 255;
    int ul = rest & (UT - 1);
    int bl = rest >> 4;
    int u = u0 + ul;

    const float* sglp = sgl + u;
    const float* mslp = msl + u;
    const float* wmp  = wm + u;
    const float* wep  = we + u;

    float num = 0.f, den = 0.f;
    int v0 = vh * (UNITS / 2);
    #pragma unroll 4
    for (int v = v0; v < v0 + UNITS / 2; ++v) {
        float s = st[bl][v];
        float a = sglp[v * UNITS];
        float m = mslp[v * UNITS];
        float t = __builtin_fmaf(-s, a, m);       // (mu - s)*sigma*log2e
        float e = __builtin_amdgcn_exp2f(t);
        float sg = __builtin_amdgcn_rcpf(1.0f + e);
        num = __builtin_fmaf(wep[v * UNITS], sg, num);
        den = __builtin_fmaf(wmp[v * UNITS], sg, den);
    }

    if (vh == 1) {
        cnum[rest] = num;
        cden[rest] = den;
    }
    __syncthreads();
    if (vh == 0) {
        num += cnum[rest];
        den += cden[rest];
        float vpre = st[bl][u];
        float g = gleak[u];
        float c = cm[u] * (float)UNFOLDS;
        int gidx = (b0 + bl) * UNITS + u;
        float numer = c * vpre + g * vleak[u] + wns[gidx] + num;
        float denom = c + g + wds[gidx] + den + EPS;
        float res = numer * __builtin_amdgcn_rcpf(denom);
        dst[gidx] = res;
        if (last && u < MOTOR) {
            out_motor[(b0 + bl) * MOTOR + u] =
                __builtin_fmaf(res, output_w[u], output_b[u]);
        }
    }
}

// ---------------------------------------------------------------------------
extern "C" void kernel_launch(void* const* d_in, const int* in_sizes, int n_in,
                              void* d_out, int out_size, void* d_ws, size_t ws_size,
                              hipStream_t stream) {
    const float* inputs   = (const float*)d_in[0];
    const float* state    = (const float*)d_in[1];
    const float* gleak    = (const float*)d_in[2];
    const float* vleak    = (const float*)d_in[3];
    const float* cm       = (const float*)d_in[4];
    const float* sigma    = (const float*)d_in[5];
    const float* mu       = (const float*)d_in[6];
    const float* w        = (const float*)d_in[7];
    const float* erev     = (const float*)d_in[8];
    const float* ssig     = (const float*)d_in[9];
    const float* smu      = (const float*)d_in[10];
    const float* sw       = (const float*)d_in[11];
    const float* serev    = (const float*)d_in[12];
    const float* input_w  = (const float*)d_in[13];
    const float* input_b  = (const float*)d_in[14];
    const float* output_w = (const float*)d_in[15];
    const float* output_b = (const float*)d_in[16];
    const float* mask     = (const float*)d_in[17];
    const float* smask    = (const float*)d_in[18];

    float* out = (float*)d_out;
    float* ws  = (float*)d_ws;

    float* sgl = ws;                        // U*U
    float* msl = sgl + UNITS * UNITS;       // U*U
    float* wm  = msl + UNITS * UNITS;       // U*U
    float* we  = wm  + UNITS * UNITS;       // U*U
    float* wns = we  + UNITS * UNITS;       // B*U
    float* wds = wns + BATCH * UNITS;       // B*U
    float* stA = wds + BATCH * UNITS;       // B*U
    float* stB = stA + BATCH * UNITS;       // B*U

    fold_kernel<<<(UNITS * UNITS + 255) / 256, 256, 0, stream>>>(
        sigma, mu, w, erev, mask, sgl, msl, wm, we);

    sensory_kernel<<<(BATCH * UNITS) / 256, 256, 0, stream>>>(
        inputs, input_w, input_b, ssig, smu, sw, serev, smask, wns, wds);

    float* state_out = out + BATCH * MOTOR;  // next_state region of d_out
    float* dsts[UNFOLDS] = {stA, stB, stA, stB, stA, state_out};

    const float* src = state;
    for (int t = 0; t < UNFOLDS; ++t) {
        int last = (t == UNFOLDS - 1) ? 1 : 0;
        unfold_kernel<<<256, 512, 0, stream>>>(
            src, dsts[t], sgl, msl, wm, we, wns, wds,
            gleak, vleak, cm, output_w, output_b, out, last);
        src = dsts[t];
    }
}

// Round 2
// 121.188 us; speedup vs baseline: 1.4031x; 1.4031x over previous
//
#include <hip/hip_runtime.h>

#define BATCH 128
#define SENS 128
#define UNITS 512
#define MOTOR 64
#define UNFOLDS 6
#define L2E 1.442695040888963f
#define EPS 1e-8f

// ---------------------------------------------------------------------------
// Fold pass: pack recurrent weights into float4 pw4[v*U+u] =
// {sigma*log2e, mu*sigma*log2e, w*mask, w*mask*erev}; same for sensory ps4;
// also precompute x[b,s] = inputs*input_w + input_b.
// ---------------------------------------------------------------------------
__global__ __launch_bounds__(256) void fold_kernel(
    const float* __restrict__ sigma, const float* __restrict__ mu,
    const float* __restrict__ w, const float* __restrict__ erev,
    const float* __restrict__ mask,
    const float* __restrict__ ssig, const float* __restrict__ smu,
    const float* __restrict__ sw, const float* __restrict__ serev,
    const float* __restrict__ smask,
    const float* __restrict__ inputs, const float* __restrict__ input_w,
    const float* __restrict__ input_b,
    float4* __restrict__ pw4, float4* __restrict__ ps4,
    float* __restrict__ x)
{
    int i = blockIdx.x * 256 + threadIdx.x;
    if (i < UNITS * UNITS) {
        float sg = sigma[i] * L2E;
        float wmv = w[i] * mask[i];
        float4 q;
        q.x = sg; q.y = mu[i] * sg; q.z = wmv; q.w = wmv * erev[i];
        pw4[i] = q;
    }
    if (i < SENS * UNITS) {
        float sg = ssig[i] * L2E;
        float wmv = sw[i] * smask[i];
        float4 q;
        q.x = sg; q.y = smu[i] * sg; q.z = wmv; q.w = wmv * serev[i];
        ps4[i] = q;
    }
    if (i < BATCH * SENS) {
        int s = i & (SENS - 1);
        x[i] = __builtin_fmaf(inputs[i], input_w[s], input_b[s]);
    }
}

// ---------------------------------------------------------------------------
// Sensory accumulators. Block tile: 8 batches x 8 units x 4 s-splits
// (256 threads).  x tile staged in LDS.  One float4 load per eval.
// ---------------------------------------------------------------------------
__global__ __launch_bounds__(256, 4) void sensory_kernel(
    const float* __restrict__ x,       // [B,S]
    const float4* __restrict__ ps4,    // [S*U]
    float* __restrict__ wns, float* __restrict__ wds)
{
    __shared__ float xs[8][SENS + 4];
    __shared__ float redn[256], redd[256];

    int bt = blockIdx.x >> 6;          // 16 batch tiles
    int ut = blockIdx.x & 63;          // 64 unit tiles
    int b0 = bt * 8;
    int u0 = ut * 8;

    // stage x rows b0..b0+7 (8*128 floats, contiguous region)
    {
        const float4* xv = (const float4*)(x + b0 * SENS);
        float4 v = xv[threadIdx.x];            // 256 float4 = 1024 floats
        int row = threadIdx.x >> 5;            // 32 float4 per row
        int col = (threadIdx.x & 31) * 4;
        xs[row][col] = v.x; xs[row][col + 1] = v.y;
        xs[row][col + 2] = v.z; xs[row][col + 3] = v.w;
    }
    __syncthreads();

    int ul = threadIdx.x & 7;
    int bl = (threadIdx.x >> 3) & 7;
    int ss = threadIdx.x >> 6;         // 0..3
    int u = u0 + ul;

    const float4* p = ps4 + u;
    float num = 0.f, den = 0.f;
    int s0 = ss * (SENS / 4);
    #pragma unroll 8
    for (int s = s0; s < s0 + SENS / 4; ++s) {
        float4 q = p[s * UNITS];
        float xv = xs[bl][s];
        float t = __builtin_fmaf(-xv, q.x, q.y);
        float e = __builtin_amdgcn_exp2f(t);
        float sg = __builtin_amdgcn_rcpf(1.0f + e);
        num = __builtin_fmaf(q.w, sg, num);
        den = __builtin_fmaf(q.z, sg, den);
    }
    redn[threadIdx.x] = num;
    redd[threadIdx.x] = den;
    __syncthreads();
    if (threadIdx.x < 64) {
        int t = threadIdx.x;
        num = redn[t] + redn[t + 64] + redn[t + 128] + redn[t + 192];
        den = redd[t] + redd[t + 64] + redd[t + 128] + redd[t + 192];
        int gidx = (b0 + bl) * UNITS + u;
        wns[gidx] = num;
        wds[gidx] = den;
    }
}

// ---------------------------------------------------------------------------
// One ODE unfold.  Block tile: 8 batches x 8 units x 4 v-splits (256 thr).
// State tile staged in LDS; one float4 weight load per eval.
// Grid 1024 blocks = 4 blocks/CU = 16 waves/CU.
// ---------------------------------------------------------------------------
__global__ __launch_bounds__(256, 4) void unfold_kernel(
    const float* __restrict__ src,     // [B,U]
    float* __restrict__ dst,           // [B,U]
    const float4* __restrict__ pw4,    // [U*U]
    const float* __restrict__ wns, const float* __restrict__ wds,
    const float* __restrict__ gleak, const float* __restrict__ vleak,
    const float* __restrict__ cm,
    const float* __restrict__ output_w, const float* __restrict__ output_b,
    float* __restrict__ out_motor,     // [B,MOTOR]
    int last)
{
    __shared__ float st[8][UNITS + 4];
    __shared__ float redn[256], redd[256];

    int bt = blockIdx.x >> 6;          // 16 batch tiles
    int ut = blockIdx.x & 63;          // 64 unit tiles
    int b0 = bt * 8;
    int u0 = ut * 8;

    // stage state rows b0..b0+7 (8*512 floats = 1024 float4, contiguous)
    {
        const float4* sv = (const float4*)(src + b0 * UNITS);
        #pragma unroll
        for (int k = 0; k < 4; ++k) {
            int idx = threadIdx.x + k * 256;
            float4 v = sv[idx];
            int row = idx >> 7;                 // 128 float4 per row
            int col = (idx & 127) * 4;
            st[row][col] = v.x; st[row][col + 1] = v.y;
            st[row][col + 2] = v.z; st[row][col + 3] = v.w;
        }
    }
    __syncthreads();

    int ul = threadIdx.x & 7;
    int bl = (threadIdx.x >> 3) & 7;
    int vs = threadIdx.x >> 6;         // 0..3
    int u = u0 + ul;

    const float4* p = pw4 + u;
    float num = 0.f, den = 0.f;
    int v0 = vs * (UNITS / 4);
    #pragma unroll 8
    for (int v = v0; v < v0 + UNITS / 4; ++v) {
        float4 q = p[(size_t)v * UNITS];
        float s = st[bl][v];
        float t = __builtin_fmaf(-s, q.x, q.y);   // (mu - s)*sigma*log2e
        float e = __builtin_amdgcn_exp2f(t);
        float sg = __builtin_amdgcn_rcpf(1.0f + e);
        num = __builtin_fmaf(q.w, sg, num);
        den = __builtin_fmaf(q.z, sg, den);
    }
    redn[threadIdx.x] = num;
    redd[threadIdx.x] = den;
    __syncthreads();
    if (threadIdx.x < 64) {
        int t = threadIdx.x;
        num = redn[t] + redn[t + 64] + redn[t + 128] + redn[t + 192];
        den = redd[t] + redd[t + 64] + redd[t + 128] + redd[t + 192];
        float vpre = st[bl][u];
        float g = gleak[u];
        float c = cm[u] * (float)UNFOLDS;
        int gidx = (b0 + bl) * UNITS + u;
        float numer = c * vpre + g * vleak[u] + wns[gidx] + num;
        float denom = c + g + wds[gidx] + den + EPS;
        float res = numer * __builtin_amdgcn_rcpf(denom);
        dst[gidx] = res;
        if (last && u < MOTOR) {
            out_motor[(b0 + bl) * MOTOR + u] =
                __builtin_fmaf(res, output_w[u], output_b[u]);
        }
    }
}

// ---------------------------------------------------------------------------
extern "C" void kernel_launch(void* const* d_in, const int* in_sizes, int n_in,
                              void* d_out, int out_size, void* d_ws, size_t ws_size,
                              hipStream_t stream) {
    const float* inputs   = (const float*)d_in[0];
    const float* state    = (const float*)d_in[1];
    const float* gleak    = (const float*)d_in[2];
    const float* vleak    = (const float*)d_in[3];
    const float* cm       = (const float*)d_in[4];
    const float* sigma    = (const float*)d_in[5];
    const float* mu       = (const float*)d_in[6];
    const float* w        = (const float*)d_in[7];
    const float* erev     = (const float*)d_in[8];
    const float* ssig     = (const float*)d_in[9];
    const float* smu      = (const float*)d_in[10];
    const float* sw       = (const float*)d_in[11];
    const float* serev    = (const float*)d_in[12];
    const float* input_w  = (const float*)d_in[13];
    const float* input_b  = (const float*)d_in[14];
    const float* output_w = (const float*)d_in[15];
    const float* output_b = (const float*)d_in[16];
    const float* mask     = (const float*)d_in[17];
    const float* smask    = (const float*)d_in[18];

    float* out = (float*)d_out;
    float* ws  = (float*)d_ws;

    float4* pw4 = (float4*)ws;                       // U*U float4
    float4* ps4 = (float4*)(ws + 4 * UNITS * UNITS); // S*U float4
    float*  x   = ws + 4 * UNITS * UNITS + 4 * SENS * UNITS;  // B*S
    float*  wns = x + BATCH * SENS;                  // B*U
    float*  wds = wns + BATCH * UNITS;               // B*U
    float*  stA = wds + BATCH * UNITS;               // B*U
    float*  stB = stA + BATCH * UNITS;               // B*U

    fold_kernel<<<(UNITS * UNITS + 255) / 256, 256, 0, stream>>>(
        sigma, mu, w, erev, mask, ssig, smu, sw, serev, smask,
        inputs, input_w, input_b, pw4, ps4, x);

    sensory_kernel<<<1024, 256, 0, stream>>>(x, ps4, wns, wds);

    float* state_out = out + BATCH * MOTOR;  // next_state region of d_out
    float* dsts[UNFOLDS] = {stA, stB, stA, stB, stA, state_out};

    const float* src = state;
    for (int t = 0; t < UNFOLDS; ++t) {
        int last = (t == UNFOLDS - 1) ? 1 : 0;
        unfold_kernel<<<1024, 256, 0, stream>>>(
            src, dsts[t], pw4, wns, wds,
            gleak, vleak, cm, output_w, output_b, out, last);
        src = dsts[t];
    }
}

// Round 3
// 82.248 us; speedup vs baseline: 2.0674x; 1.4734x over previous
//
#include <hip/hip_runtime.h>

#define BATCH 128
#define SENS 128
#define UNITS 512
#define MOTOR 64
#define UNFOLDS 6
#define L2E 1.442695040888963f
#define EPS 1e-8f

#define BT 8      // batches per block (register-blocked)
#define UT 8      // units per block
#define STP 12    // transposed LDS row stride (8 data + 4 pad; 48B = 16B-aligned,
                  // 12*v mod 32 spreads the wave's 8 v-groups over 8 disjoint bank quads)

// ---------------------------------------------------------------------------
// Fold pass: pw4[v*U+u] = {sigma*log2e, mu*sigma*log2e, w*mask, w*mask*erev};
// ps4 likewise for sensory; x[b,s] = inputs*input_w + input_b.
// ---------------------------------------------------------------------------
__global__ __launch_bounds__(256) void fold_kernel(
    const float* __restrict__ sigma, const float* __restrict__ mu,
    const float* __restrict__ w, const float* __restrict__ erev,
    const float* __restrict__ mask,
    const float* __restrict__ ssig, const float* __restrict__ smu,
    const float* __restrict__ sw, const float* __restrict__ serev,
    const float* __restrict__ smask,
    const float* __restrict__ inputs, const float* __restrict__ input_w,
    const float* __restrict__ input_b,
    float4* __restrict__ pw4, float4* __restrict__ ps4,
    float* __restrict__ x)
{
    int i = blockIdx.x * 256 + threadIdx.x;
    if (i < UNITS * UNITS) {
        float sg = sigma[i] * L2E;
        float wmv = w[i] * mask[i];
        float4 q;
        q.x = sg; q.y = mu[i] * sg; q.z = wmv; q.w = wmv * erev[i];
        pw4[i] = q;
    }
    if (i < SENS * UNITS) {
        float sg = ssig[i] * L2E;
        float wmv = sw[i] * smask[i];
        float4 q;
        q.x = sg; q.y = smu[i] * sg; q.z = wmv; q.w = wmv * serev[i];
        ps4[i] = q;
    }
    if (i < BATCH * SENS) {
        int s = i & (SENS - 1);
        x[i] = __builtin_fmaf(inputs[i], input_w[s], input_b[s]);
    }
}

// ---------------------------------------------------------------------------
// Sensory accumulators.  256 thr = 8 u x 32 s-groups; each thread computes
// 8 batches in registers; weights loaded once per block (no duplication).
// ---------------------------------------------------------------------------
__global__ __launch_bounds__(256, 4) void sensory_kernel(
    const float* __restrict__ x,       // [B,S]
    const float4* __restrict__ ps4,    // [S*U]
    float* __restrict__ wns, float* __restrict__ wds)
{
    __shared__ __align__(16) float xsT[SENS][STP];   // x transposed: [s][b]
    __shared__ float2 red[4][BT][UT];

    int phys = blockIdx.x;                    // 1024 blocks, 8 XCDs
    int logical = (phys & 7) * 128 + (phys >> 3);   // bijective XCD chunking
    int ut = logical >> 4;                    // 0..63
    int bt = logical & 15;                    // 0..15
    int b0 = bt * BT;
    int u0 = ut * UT;

    // stage x rows b0..b0+7 transposed: thread = (b = tid&7, s4 = tid>>3)
    {
        const float4* xv = (const float4*)(x + b0 * SENS);
        int bl = threadIdx.x & 7;
        int s4 = threadIdx.x >> 3;            // 0..31
        float4 t = xv[bl * (SENS / 4) + s4];
        xsT[s4 * 4 + 0][bl] = t.x;
        xsT[s4 * 4 + 1][bl] = t.y;
        xsT[s4 * 4 + 2][bl] = t.z;
        xsT[s4 * 4 + 3][bl] = t.w;
    }
    __syncthreads();

    int ul = threadIdx.x & 7;
    int ss = threadIdx.x >> 3;                // 0..31
    int u = u0 + ul;

    float num[BT], den[BT];
    #pragma unroll
    for (int b = 0; b < BT; ++b) { num[b] = 0.f; den[b] = 0.f; }

    const float4* pv = ps4 + (size_t)ss * UNITS + u;
    const float* srow = &xsT[ss][0];
    #pragma unroll
    for (int i = 0; i < SENS / 32; ++i) {     // s = ss + 32*i
        float4 q = pv[0];
        pv += 32 * UNITS;
        const float4* sp = (const float4*)srow;
        float4 xa = sp[0];
        float4 xb = sp[1];
        srow += 32 * STP;
        float sarr[8] = {xa.x, xa.y, xa.z, xa.w, xb.x, xb.y, xb.z, xb.w};
        #pragma unroll
        for (int b = 0; b < BT; ++b) {
            float t = __builtin_fmaf(-sarr[b], q.x, q.y);
            float e = __builtin_amdgcn_exp2f(t);
            float sg = __builtin_amdgcn_rcpf(1.0f + e);
            num[b] = __builtin_fmaf(q.w, sg, num[b]);
            den[b] = __builtin_fmaf(q.z, sg, den[b]);
        }
    }

    // reduce across the wave's 8 s-groups (lane bits 3,4,5)
    #pragma unroll
    for (int b = 0; b < BT; ++b) {
        #pragma unroll
        for (int m = 8; m <= 32; m <<= 1) {
            num[b] += __shfl_xor(num[b], m, 64);
            den[b] += __shfl_xor(den[b], m, 64);
        }
    }
    int lane = threadIdx.x & 63;
    int wid = threadIdx.x >> 6;               // 0..3
    if (lane < 8) {
        #pragma unroll
        for (int b = 0; b < BT; ++b)
            red[wid][b][lane] = make_float2(num[b], den[b]);
    }
    __syncthreads();
    if (threadIdx.x < 64) {
        int uu = threadIdx.x & 7;
        int bb = threadIdx.x >> 3;
        float n = 0.f, d = 0.f;
        #pragma unroll
        for (int k = 0; k < 4; ++k) {
            float2 v = red[k][bb][uu];
            n += v.x; d += v.y;
        }
        int gidx = (b0 + bb) * UNITS + (u0 + uu);
        wns[gidx] = n;
        wds[gidx] = d;
    }
}

// ---------------------------------------------------------------------------
// One ODE unfold.  256 thr = 8 u x 32 v-groups (v strided by 32); each thread
// computes 8 batches in registers.  Weight float4 loaded once per block.
// ---------------------------------------------------------------------------
__global__ __launch_bounds__(256, 4) void unfold_kernel(
    const float* __restrict__ src,     // [B,U]
    float* __restrict__ dst,           // [B,U]
    const float4* __restrict__ pw4,    // [U*U]
    const float* __restrict__ wns, const float* __restrict__ wds,
    const float* __restrict__ gleak, const float* __restrict__ vleak,
    const float* __restrict__ cm,
    const float* __restrict__ output_w, const float* __restrict__ output_b,
    float* __restrict__ out_motor,     // [B,MOTOR]
    int last)
{
    __shared__ __align__(16) float stT[UNITS][STP];  // state transposed: [v][b]
    __shared__ float2 red[4][BT][UT];

    int phys = blockIdx.x;                    // 1024 blocks
    int logical = (phys & 7) * 128 + (phys >> 3);   // XCD gets 8 u-tiles x 16 b-tiles
    int ut = logical >> 4;                    // 0..63
    int bt = logical & 15;                    // 0..15
    int b0 = bt * BT;
    int u0 = ut * UT;

    // stage state rows b0..b0+7 transposed: thread = (b = tid&7, v4 = tid>>3 + 32k)
    {
        const float4* sv = (const float4*)(src + (size_t)b0 * UNITS);
        int bl = threadIdx.x & 7;
        int v4b = threadIdx.x >> 3;           // 0..31
        #pragma unroll
        for (int k = 0; k < 4; ++k) {
            int v4 = v4b + 32 * k;            // 0..127
            float4 t = sv[bl * (UNITS / 4) + v4];
            stT[v4 * 4 + 0][bl] = t.x;
            stT[v4 * 4 + 1][bl] = t.y;
            stT[v4 * 4 + 2][bl] = t.z;
            stT[v4 * 4 + 3][bl] = t.w;
        }
    }
    __syncthreads();

    int ul = threadIdx.x & 7;
    int vs = threadIdx.x >> 3;                // 0..31
    int u = u0 + ul;

    float num[BT], den[BT];
    #pragma unroll
    for (int b = 0; b < BT; ++b) { num[b] = 0.f; den[b] = 0.f; }

    const float4* pv = pw4 + (size_t)vs * UNITS + u;
    const float* srow = &stT[vs][0];
    #pragma unroll 4
    for (int i = 0; i < UNITS / 32; ++i) {    // v = vs + 32*i
        float4 q = pv[0];
        pv += 32 * UNITS;
        const float4* sp = (const float4*)srow;
        float4 xa = sp[0];
        float4 xb = sp[1];
        srow += 32 * STP;
        float sarr[8] = {xa.x, xa.y, xa.z, xa.w, xb.x, xb.y, xb.z, xb.w};
        #pragma unroll
        for (int b = 0; b < BT; ++b) {
            float t = __builtin_fmaf(-sarr[b], q.x, q.y);  // (mu - s)*sigma*log2e
            float e = __builtin_amdgcn_exp2f(t);
            float sg = __builtin_amdgcn_rcpf(1.0f + e);
            num[b] = __builtin_fmaf(q.w, sg, num[b]);
            den[b] = __builtin_fmaf(q.z, sg, den[b]);
        }
    }

    // reduce across the wave's 8 v-groups
    #pragma unroll
    for (int b = 0; b < BT; ++b) {
        #pragma unroll
        for (int m = 8; m <= 32; m <<= 1) {
            num[b] += __shfl_xor(num[b], m, 64);
            den[b] += __shfl_xor(den[b], m, 64);
        }
    }
    int lane = threadIdx.x & 63;
    int wid = threadIdx.x >> 6;               // 0..3
    if (lane < 8) {
        #pragma unroll
        for (int b = 0; b < BT; ++b)
            red[wid][b][lane] = make_float2(num[b], den[b]);
    }
    __syncthreads();
    if (threadIdx.x < 64) {
        int uu = threadIdx.x & 7;
        int bb = threadIdx.x >> 3;
        float n = 0.f, d = 0.f;
        #pragma unroll
        for (int k = 0; k < 4; ++k) {
            float2 v = red[k][bb][uu];
            n += v.x; d += v.y;
        }
        int gu = u0 + uu;
        int gb = b0 + bb;
        float vpre = stT[gu][bb];
        float g = gleak[gu];
        float c = cm[gu] * (float)UNFOLDS;
        int gidx = gb * UNITS + gu;
        float numer = __builtin_fmaf(c, vpre,
                        __builtin_fmaf(g, vleak[gu], wns[gidx] + n));
        float denom = c + g + wds[gidx] + d + EPS;
        float res = numer * __builtin_amdgcn_rcpf(denom);
        dst[gidx] = res;
        if (last && gu < MOTOR) {
            out_motor[gb * MOTOR + gu] =
                __builtin_fmaf(res, output_w[gu], output_b[gu]);
        }
    }
}

// ---------------------------------------------------------------------------
extern "C" void kernel_launch(void* const* d_in, const int* in_sizes, int n_in,
                              void* d_out, int out_size, void* d_ws, size_t ws_size,
                              hipStream_t stream) {
    const float* inputs   = (const float*)d_in[0];
    const float* state    = (const float*)d_in[1];
    const float* gleak    = (const float*)d_in[2];
    const float* vleak    = (const float*)d_in[3];
    const float* cm       = (const float*)d_in[4];
    const float* sigma    = (const float*)d_in[5];
    const float* mu       = (const float*)d_in[6];
    const float* w        = (const float*)d_in[7];
    const float* erev     = (const float*)d_in[8];
    const float* ssig     = (const float*)d_in[9];
    const float* smu      = (const float*)d_in[10];
    const float* sw       = (const float*)d_in[11];
    const float* serev    = (const float*)d_in[12];
    const float* input_w  = (const float*)d_in[13];
    const float* input_b  = (const float*)d_in[14];
    const float* output_w = (const float*)d_in[15];
    const float* output_b = (const float*)d_in[16];
    const float* mask     = (const float*)d_in[17];
    const float* smask    = (const float*)d_in[18];

    float* out = (float*)d_out;
    float* ws  = (float*)d_ws;

    float4* pw4 = (float4*)ws;                       // U*U float4
    float4* ps4 = (float4*)(ws + 4 * UNITS * UNITS); // S*U float4
    float*  x   = ws + 4 * UNITS * UNITS + 4 * SENS * UNITS;  // B*S
    float*  wns = x + BATCH * SENS;                  // B*U
    float*  wds = wns + BATCH * UNITS;               // B*U
    float*  stA = wds + BATCH * UNITS;               // B*U
    float*  stB = stA + BATCH * UNITS;               // B*U

    fold_kernel<<<(UNITS * UNITS + 255) / 256, 256, 0, stream>>>(
        sigma, mu, w, erev, mask, ssig, smu, sw, serev, smask,
        inputs, input_w, input_b, pw4, ps4, x);

    sensory_kernel<<<1024, 256, 0, stream>>>(x, ps4, wns, wds);

    float* state_out = out + BATCH * MOTOR;  // next_state region of d_out
    float* dsts[UNFOLDS] = {stA, stB, stA, stB, stA, state_out};

    const float* src = state;
    for (int t = 0; t < UNFOLDS; ++t) {
        int last = (t == UNFOLDS - 1) ? 1 : 0;
        unfold_kernel<<<1024, 256, 0, stream>>>(
            src, dsts[t], pw4, wns, wds,
            gleak, vleak, cm, output_w, output_b, out, last);
        src = dsts[t];
    }
}